// Round 5
// baseline (457.834 us; speedup 1.0000x reference)
//
#include <hip/hip_runtime.h>

// GNN layer: messages = relu(NF @ Wm^T + bm); agg = (adj @ messages)/deg; GRU(agg, NF)
// N=8192, D=128. k2 memory-bound on adj (268 MB int32) -> ~43 us floor.
// k2 v5 (AITER-style): 3-deep LDS ring, RAW s_barrier + manual s_waitcnt vmcnt(8/4/0)
// -- vmcnt never drains to 0 mid-loop, so the global_load_lds queue stays 2-3 steps
// deep across barriers (rounds 3/4 failure: __syncthreads emits vmcnt(0) each step,
// emptying the HBM pipe -> 3x latency-exposed).

#define NN 8192
#define DIM 128
#define LSTR 136     // k1/k3 LDS row stride (shorts)
#define KSPLIT 4
#define NSTEP 64     // (8192/KSPLIT)/32 steps of K=32

typedef __bf16 bf16x8 __attribute__((ext_vector_type(8)));
typedef float f32x4 __attribute__((ext_vector_type(4)));

__device__ __forceinline__ unsigned short f2bf(float f) {
  union { float f; unsigned u; } v; v.f = f;
  unsigned r = v.u + 0x7FFF + ((v.u >> 16) & 1);  // RNE
  return (unsigned short)(r >> 16);
}
__device__ __forceinline__ float sigmoidf_(float x) {
  return 1.0f / (1.0f + __expf(-x));
}
__device__ __forceinline__ float tanhf_(float x) {
  float e = __expf(-2.0f * fabsf(x));
  float r = (1.0f - e) / (1.0f + e);
  return x < 0.0f ? -r : r;
}
__device__ __forceinline__ void pack4(float4 v, unsigned short* dst) {
  dst[0] = f2bf(v.x); dst[1] = f2bf(v.y); dst[2] = f2bf(v.z); dst[3] = f2bf(v.w);
}
// async 16B/lane global->LDS DMA; lds dest wave-uniform (HW adds lane*16)
__device__ __forceinline__ void async16(const void* g, void* l) {
  __builtin_amdgcn_global_load_lds(
      (const __attribute__((address_space(1))) unsigned int*)g,
      (__attribute__((address_space(3))) unsigned int*)l, 16, 0, 0);
}

// ---------------- K1: msgT[o][m] = relu(NF @ Wm^T + bm) bf16, coalesced stores
__global__ __launch_bounds__(256) void k1_msg(
    const float* __restrict__ nf, const float* __restrict__ w_msg,
    const float* __restrict__ b_msg, unsigned short* __restrict__ msgT) {
  __shared__ unsigned short wm[128 * LSTR];   // wm[o][k]; reused as T[o][m] (stride 72)
  __shared__ unsigned short nfl[64 * LSTR];
  const int t = threadIdx.x;
  const int m0 = blockIdx.x * 64;
  const float4* wm4 = (const float4*)w_msg;
  const float4* nf4 = (const float4*)nf;
  for (int i = t; i < 4096; i += 256)
    pack4(wm4[i], &wm[(i >> 5) * LSTR + (i & 31) * 4]);
  for (int i = t; i < 2048; i += 256)
    pack4(nf4[m0 * 32 + i], &nfl[(i >> 5) * LSTR + (i & 31) * 4]);
  __syncthreads();
  const int lane = t & 63, wave = t >> 6;
  const int quad = lane >> 4, l16 = lane & 15;
  const int rt = wave;
  f32x4 acc[8];
  for (int j = 0; j < 8; ++j) acc[j] = (f32x4){0.f, 0.f, 0.f, 0.f};
  for (int kk = 0; kk < 4; ++kk) {
    bf16x8 a = *(const bf16x8*)&nfl[(rt * 16 + l16) * LSTR + kk * 32 + quad * 8];
    for (int ct = 0; ct < 8; ++ct) {
      bf16x8 b = *(const bf16x8*)&wm[(ct * 16 + l16) * LSTR + kk * 32 + quad * 8];
      acc[ct] = __builtin_amdgcn_mfma_f32_16x16x32_bf16(a, b, acc[ct], 0, 0, 0);
    }
  }
  __syncthreads();
  for (int ct = 0; ct < 8; ++ct) {
    const int o = ct * 16 + l16;
    const float bias = b_msg[o];
    for (int r = 0; r < 4; ++r)
      wm[o * 72 + rt * 16 + quad * 4 + r] = f2bf(fmaxf(acc[ct][r] + bias, 0.0f));
  }
  __syncthreads();
  for (int i = t; i < 1024; i += 256) {
    const int o = i >> 3, seg = i & 7;
    *(int4*)&msgT[o * NN + m0 + seg * 8] = *(const int4*)&wm[o * 72 + seg * 8];
  }
}

// ---------------- K2 v5: 3-deep ring, raw barriers, vmcnt never 0 mid-loop
__global__ __launch_bounds__(256, 2) void k2_agg(
    const int* __restrict__ adj, const unsigned short* __restrict__ msgT,
    float* __restrict__ part, int* __restrict__ degp) {
  __shared__ int aT[3][64 * 32];              // [m][32 k-ints, 8 swizzled 16B slots] 8 KB
  __shared__ unsigned short bT[3][128 * 32];  // [o][32 k-bf16, 4 swizzled 16B slots] 8 KB
  const int t = threadIdx.x;
  const int lane = t & 63, wave = t >> 6;
  const int quad = lane >> 4, l16 = lane & 15;
  const int mt = blockIdx.x >> 2, split = blockIdx.x & 3;
  const int m0 = mt * 64, kb = split * (NN / KSPLIT);

  // staging descriptors (2 A + 2 B issues per wave per step = G=4)
  const int* aSrc[2];
  const unsigned short* bSrc[2];
  int segOff[2];
#pragma unroll
  for (int j = 0; j < 2; ++j) {
    const int seg = wave * 2 + j;                       // 0..7
    const int ra = seg * 8 + (lane >> 3);               // A row_local 0..63
    const int ca = (lane & 7) ^ (ra & 7);               // logical 16B chunk (4 ints)
    aSrc[j] = adj + (size_t)(m0 + ra) * NN + kb + ca * 4;
    const int ob = seg * 16 + (lane >> 2);              // B row o 0..127
    const int cbk = (lane & 3) ^ ((ob ^ (ob >> 2)) & 3); // logical 16B chunk (8 shorts)
    bSrc[j] = msgT + (size_t)ob * NN + kb + cbk * 8;
    segOff[j] = seg * 1024;                             // LDS byte offset (wave-uniform)
  }

  f32x4 acc[8];
#pragma unroll
  for (int j = 0; j < 8; ++j) acc[j] = (f32x4){0.f, 0.f, 0.f, 0.f};
  int deg = 0;

#define ISSUE(g, b)                                                         \
  {                                                                         \
    const int _ko = (g) * 32;                                               \
    async16(aSrc[0] + _ko, (char*)&aT[(b)][0] + segOff[0]);                 \
    async16(aSrc[1] + _ko, (char*)&aT[(b)][0] + segOff[1]);                 \
    async16(bSrc[0] + _ko, (char*)&bT[(b)][0] + segOff[0]);                 \
    async16(bSrc[1] + _ko, (char*)&bT[(b)][0] + segOff[1]);                 \
  }

  const int rA = wave * 16 + l16;          // this lane's A row (local)
  const int sA0 = ((2 * quad) ^ (rA & 7)) * 4;
  const int sA1 = ((2 * quad + 1) ^ (rA & 7)) * 4;
  const int slotB = (quad ^ ((l16 ^ (l16 >> 2)) & 3)) * 8;

#define COMPUTE(b)                                                          \
  {                                                                         \
    int4 A0 = *(const int4*)&aT[(b)][rA * 32 + sA0];                        \
    int4 A1 = *(const int4*)&aT[(b)][rA * 32 + sA1];                        \
    union { bf16x8 v; unsigned short u[8]; } a;                             \
    a.u[0] = A0.x ? 0x3F80 : 0; a.u[1] = A0.y ? 0x3F80 : 0;                 \
    a.u[2] = A0.z ? 0x3F80 : 0; a.u[3] = A0.w ? 0x3F80 : 0;                 \
    a.u[4] = A1.x ? 0x3F80 : 0; a.u[5] = A1.y ? 0x3F80 : 0;                 \
    a.u[6] = A1.z ? 0x3F80 : 0; a.u[7] = A1.w ? 0x3F80 : 0;                 \
    deg += A0.x + A0.y + A0.z + A0.w + A1.x + A1.y + A1.z + A1.w;           \
    _Pragma("unroll")                                                       \
    for (int ct = 0; ct < 8; ++ct) {                                        \
      bf16x8 bb = *(const bf16x8*)&bT[(b)][(ct * 16 + l16) * 32 + slotB];   \
      acc[ct] = __builtin_amdgcn_mfma_f32_16x16x32_bf16(a.v, bb, acc[ct], 0, 0, 0); \
    }                                                                       \
  }

  // prologue: fill the ring
  ISSUE(0, 0);
  ISSUE(1, 1);
  ISSUE(2, 2);

  int b = 0;
  for (int s = 0; s <= NSTEP - 4; ++s) {   // s = 0..60
    asm volatile("s_waitcnt vmcnt(8)" ::: "memory");   // oldest group landed; 2 in flight
    asm volatile("s_barrier" ::: "memory");            // all waves' group-s data visible
    COMPUTE(b);
    asm volatile("s_waitcnt lgkmcnt(0)\n\ts_barrier" ::: "memory");  // buf free to reuse
    ISSUE(s + 3, b);
    b = (b == 2) ? 0 : b + 1;
  }
  // tail: s = 61, 62, 63
  asm volatile("s_waitcnt vmcnt(8)" ::: "memory");
  asm volatile("s_barrier" ::: "memory");
  COMPUTE(b);
  b = (b == 2) ? 0 : b + 1;
  asm volatile("s_waitcnt vmcnt(4)" ::: "memory");
  asm volatile("s_barrier" ::: "memory");
  COMPUTE(b);
  b = (b == 2) ? 0 : b + 1;
  asm volatile("s_waitcnt vmcnt(0)" ::: "memory");
  asm volatile("s_barrier" ::: "memory");
  COMPUTE(b);
#undef ISSUE
#undef COMPUTE

  // degree: quads hold k-partials of row wave*16+l16 within this split's range
  deg += __shfl_xor(deg, 16, 64);
  deg += __shfl_xor(deg, 32, 64);
  if (lane < 16) degp[split * NN + m0 + wave * 16 + lane] = deg;
  float* pp = part + (size_t)split * NN * DIM;
#pragma unroll
  for (int ct = 0; ct < 8; ++ct)
    for (int r = 0; r < 4; ++r)
      pp[(m0 + wave * 16 + quad * 4 + r) * DIM + ct * 16 + l16] = acc[ct][r];
}

// ---------------- K3: fused GRU; agg assembled from KSPLIT fp32 partials + degree.
__global__ __launch_bounds__(256) void k3_gru(
    const float* __restrict__ nf, const float* __restrict__ part,
    const int* __restrict__ degp,
    const float* __restrict__ w_ih, const float* __restrict__ w_hh,
    const float* __restrict__ b_ih, const float* __restrict__ b_hh,
    float* __restrict__ out) {
  __shared__ unsigned short aggL[32 * LSTR];
  __shared__ unsigned short nfL[32 * LSTR];
  __shared__ unsigned short wL[128 * LSTR];
  __shared__ float invD[32];
  const int t = threadIdx.x;
  const int m0 = blockIdx.x * 32;
  if (t < 32) {
    int d = 0;
    for (int sp = 0; sp < KSPLIT; ++sp) d += degp[sp * NN + m0 + t];
    invD[t] = 1.0f / (float)(d > 1 ? d : 1);
  }
  __syncthreads();
  const float4* p4 = (const float4*)part;
  const float4* nf4 = (const float4*)nf;
  for (int u = t; u < 1024; u += 256) {   // 32 rows x 32 float4
    const int m = u >> 5;
    const int gi = (m0 + m) * 32 + (u & 31);
    float4 s = p4[gi];
    for (int sp = 1; sp < KSPLIT; ++sp) {
      float4 q = p4[sp * (NN * DIM / 4) + gi];
      s.x += q.x; s.y += q.y; s.z += q.z; s.w += q.w;
    }
    const float iv = invD[m];
    s.x *= iv; s.y *= iv; s.z *= iv; s.w *= iv;
    pack4(s, &aggL[m * LSTR + (u & 31) * 4]);
  }
  for (int u = t; u < 1024; u += 256) {
    const int m = u >> 5;
    pack4(nf4[(m0 + m) * 32 + (u & 31)], &nfL[m * LSTR + (u & 31) * 4]);
  }

  const int lane = t & 63, wave = t >> 6;
  const int quad = lane >> 4, l16 = lane & 15;
  const int rt = wave >> 1;
  const int cb = (wave & 1) * 4;
  const int aOff = (rt * 16 + l16) * LSTR + quad * 8;
  const float4* wih4 = (const float4*)w_ih;
  const float4* whh4 = (const float4*)w_hh;

  float gate[4][4];
  const int order[3] = {0, 2, 1};  // r -> n -> z
  for (int ci = 0; ci < 3; ++ci) {
    const int c = order[ci];
    __syncthreads();
    for (int u = t; u < 4096; u += 256)
      pack4(wih4[c * 4096 + u], &wL[(u >> 5) * LSTR + (u & 31) * 4]);
    __syncthreads();
    f32x4 ai[4];
    {
      bf16x8 a[4];
      for (int kk = 0; kk < 4; ++kk) a[kk] = *(const bf16x8*)&aggL[aOff + kk * 32];
      for (int j = 0; j < 4; ++j) {
        f32x4 acc = (f32x4){0.f, 0.f, 0.f, 0.f};
        const int ct = cb + j;
        for (int kk = 0; kk < 4; ++kk) {
          bf16x8 bz = *(const bf16x8*)&wL[(ct * 16 + l16) * LSTR + kk * 32 + quad * 8];
          acc = __builtin_amdgcn_mfma_f32_16x16x32_bf16(a[kk], bz, acc, 0, 0, 0);
        }
        ai[j] = acc;
      }
    }
    __syncthreads();
    for (int u = t; u < 4096; u += 256)
      pack4(whh4[c * 4096 + u], &wL[(u >> 5) * LSTR + (u & 31) * 4]);
    __syncthreads();
    f32x4 ah[4];
    {
      bf16x8 a[4];
      for (int kk = 0; kk < 4; ++kk) a[kk] = *(const bf16x8*)&nfL[aOff + kk * 32];
      for (int j = 0; j < 4; ++j) {
        f32x4 acc = (f32x4){0.f, 0.f, 0.f, 0.f};
        const int ct = cb + j;
        for (int kk = 0; kk < 4; ++kk) {
          bf16x8 bz = *(const bf16x8*)&wL[(ct * 16 + l16) * LSTR + kk * 32 + quad * 8];
          acc = __builtin_amdgcn_mfma_f32_16x16x32_bf16(a[kk], bz, acc, 0, 0, 0);
        }
        ah[j] = acc;
      }
    }
    for (int j = 0; j < 4; ++j) {
      const int col = (cb + j) * 16 + l16;
      const float bi = b_ih[c * 128 + col];
      const float bh = b_hh[c * 128 + col];
      for (int r = 0; r < 4; ++r) {
        const float gi = ai[j][r] + bi;
        const float gh = ah[j][r] + bh;
        if (c == 0) {
          gate[j][r] = sigmoidf_(gi + gh);
        } else if (c == 2) {
          gate[j][r] = tanhf_(gi + gate[j][r] * gh);
        } else {
          const float z = sigmoidf_(gi + gh);
          const int m = m0 + rt * 16 + quad * 4 + r;
          const float h = nf[m * 128 + col];
          out[m * 128 + col] = (1.0f - z) * gate[j][r] + z * h;
        }
      }
    }
  }
}

extern "C" void kernel_launch(void* const* d_in, const int* in_sizes, int n_in,
                              void* d_out, int out_size, void* d_ws, size_t ws_size,
                              hipStream_t stream) {
  const float* nf   = (const float*)d_in[0];
  const int*   adj  = (const int*)d_in[1];
  const float* wmsg = (const float*)d_in[2];
  const float* bmsg = (const float*)d_in[3];
  const float* wih  = (const float*)d_in[4];
  const float* whh  = (const float*)d_in[5];
  const float* bih  = (const float*)d_in[6];
  const float* bhh  = (const float*)d_in[7];
  float* out = (float*)d_out;

  char* ws = (char*)d_ws;
  unsigned short* msgT = (unsigned short*)ws;              // bf16 [128][8192]     2 MB
  float* part = (float*)(ws + (size_t)2 * 1024 * 1024);    // f32 [4][8192][128]  16 MB
  int* degp   = (int*)(ws + (size_t)18 * 1024 * 1024);     // int [4][8192]      128 KB

  k1_msg<<<NN / 64, 256, 0, stream>>>(nf, wmsg, bmsg, msgT);
  k2_agg<<<(NN / 64) * KSPLIT, 256, 0, stream>>>(adj, msgT, part, degp);
  k3_gru<<<NN / 32, 256, 0, stream>>>(nf, part, degp, wih, whh, bih, bhh, out);
}